// Round 1
// baseline (99.839 us; speedup 1.0000x reference)
//
#include <hip/hip_runtime.h>
#include <math.h>

// Ewald real-space pair sum:
//   pot = NORM/(4*pi) * sum_{i != j} dot(q_i, q_j) * erf(d_ij / sqrt(2)) / d_ij
// n = 4096, n_q = 8. Inputs fp32. Output: single fp32 scalar.

#define N_Q    8
#define BLOCK  256   // threads per block = i-tile size
#define JCHUNK 128   // j rows staged in LDS per block

__global__ void zero_ws_kernel(double* ws) {
    if (threadIdx.x == 0) ws[0] = 0.0;
}

__global__ __launch_bounds__(BLOCK) void ewald_pairs_kernel(
    const float* __restrict__ q,   // [n][N_Q]
    const float* __restrict__ r,   // [n][3]
    double* __restrict__ ws,       // [1] accumulator
    int n)
{
    __shared__ float s_q[JCHUNK][N_Q];   // 4 KB
    __shared__ float s_r[JCHUNK][3];     // 1.5 KB
    __shared__ float s_part[BLOCK / 64];

    const int tid = threadIdx.x;
    const int i   = blockIdx.x * BLOCK + tid;
    const int j0  = blockIdx.y * JCHUNK;

    // ---- stage j-chunk into LDS ----
    // q chunk: JCHUNK*N_Q = 1024 floats = 256 float4, one per thread.
    {
        const float4* qg = reinterpret_cast<const float4*>(q + (size_t)j0 * N_Q);
        reinterpret_cast<float4*>(&s_q[0][0])[tid] = qg[tid];
    }
    // r chunk: JCHUNK*3 = 384 floats.
    for (int idx = tid; idx < JCHUNK * 3; idx += BLOCK) {
        s_r[idx / 3][idx % 3] = r[(size_t)(j0 + idx / 3) * 3 + (idx % 3)];
    }
    __syncthreads();

    // ---- per-thread i data ----
    float rx = 0.f, ry = 0.f, rz = 0.f;
    float qi[N_Q];
    if (i < n) {
        rx = r[(size_t)i * 3 + 0];
        ry = r[(size_t)i * 3 + 1];
        rz = r[(size_t)i * 3 + 2];
        const float4* qgi = reinterpret_cast<const float4*>(q + (size_t)i * N_Q);
        float4 a = qgi[0], b = qgi[1];
        qi[0] = a.x; qi[1] = a.y; qi[2] = a.z; qi[3] = a.w;
        qi[4] = b.x; qi[5] = b.y; qi[6] = b.z; qi[7] = b.w;
    }

    const float inv_sqrt2 = 0.70710678118654752f;
    float acc = 0.0f;

    if (i < n) {
#pragma unroll 4
        for (int jj = 0; jj < JCHUNK; ++jj) {
            const int j = j0 + jj;
            float dx = s_r[jj][0] - rx;
            float dy = s_r[jj][1] - ry;
            float dz = s_r[jj][2] - rz;
            float d2 = dx * dx + dy * dy + dz * dz;

            float dot = 0.0f;
#pragma unroll
            for (int c = 0; c < N_Q; ++c) dot += qi[c] * s_q[jj][c];

            if (j != i) {
                float d = sqrtf(d2);
                acc += dot * (erff(d * inv_sqrt2) / d);
            }
        }
    }

    // ---- block reduction ----
    for (int off = 32; off > 0; off >>= 1)
        acc += __shfl_down(acc, off, 64);
    if ((tid & 63) == 0) s_part[tid >> 6] = acc;
    __syncthreads();
    if (tid == 0) {
        float t = s_part[0] + s_part[1] + s_part[2] + s_part[3];
        atomicAdd(ws, (double)t);
    }
}

__global__ void finalize_kernel(const double* __restrict__ ws, float* __restrict__ out) {
    if (threadIdx.x == 0) {
        // NORM_FACTOR / (2*pi) / 2
        const double scale = 90.0474 / (2.0 * 3.14159265358979323846) / 2.0;
        out[0] = (float)(ws[0] * scale);
    }
}

extern "C" void kernel_launch(void* const* d_in, const int* in_sizes, int n_in,
                              void* d_out, int out_size, void* d_ws, size_t ws_size,
                              hipStream_t stream) {
    const float* q = (const float*)d_in[0];   // [n, 8]
    const float* r = (const float*)d_in[1];   // [n, 3]
    // d_in[2] = cell (singular -> real-space branch), unused.
    float*  out = (float*)d_out;
    double* ws  = (double*)d_ws;

    const int n = in_sizes[1] / 3;            // 4096

    zero_ws_kernel<<<1, 1, 0, stream>>>(ws);

    dim3 grid((n + BLOCK - 1) / BLOCK, (n + JCHUNK - 1) / JCHUNK);
    ewald_pairs_kernel<<<grid, BLOCK, 0, stream>>>(q, r, ws, n);

    finalize_kernel<<<1, 1, 0, stream>>>(ws, out);
}

// Round 2
// 75.722 us; speedup vs baseline: 1.3185x; 1.3185x over previous
//
#include <hip/hip_runtime.h>
#include <math.h>

// Ewald real-space pair sum, symmetric half-enumeration:
//   out = (NORM / 2pi) * sum_{i<j} dot(q_i,q_j) * erf(d_ij/sqrt(2)) / d_ij
// n = 4096, n_q = 8, fp32. Branchless erf (Abramowitz-Stegun 7.1.26, |err|<=1.5e-7).

#define TILE   256
#define KC     64
#define CHUNKS (TILE / KC)   // 4

__global__ __launch_bounds__(256) void ewald_pairs_kernel(
    const float* __restrict__ q,   // [n][8]
    const float* __restrict__ r,   // [n][3]
    float* __restrict__ partials,  // [gridDim.x]
    int n)
{
    __shared__ float s_q[KC][8];   // j-chunk charges, 2 KB
    __shared__ float s_r[KC][4];   // j-chunk coords (padded for b128), 1 KB
    __shared__ float s_part[4];

    const int tid = threadIdx.x;
    const int rid   = blockIdx.x / CHUNKS;
    const int chunk = blockIdx.x % CHUNKS;

    // triangular decode: rid -> (col<=row) over tile pairs
    int row = (int)((sqrtf(8.0f * (float)rid + 1.0f) - 1.0f) * 0.5f);
    while ((row + 1) * (row + 2) / 2 <= rid) ++row;
    while (row * (row + 1) / 2 > rid) --row;
    const int col = rid - row * (row + 1) / 2;

    const int ti = col, tj = row;          // ti <= tj; off-diag => every i<j valid
    const bool diag = (ti == tj);

    const int i  = ti * TILE + tid;
    const int j0 = tj * TILE + chunk * KC;

    // ---- stage j-chunk ----
    if (tid < KC * 2) {  // q: KC*8 floats = 128 float4
        reinterpret_cast<float4*>(&s_q[0][0])[tid] =
            reinterpret_cast<const float4*>(q + (size_t)j0 * 8)[tid];
    }
    if (tid >= 64 && tid < 64 + KC * 3) {  // r: 192 scalars into padded [KC][4]
        const int t = tid - 64;
        s_r[t / 3][t % 3] = r[(size_t)j0 * 3 + t];
    }
    __syncthreads();

    // ---- per-thread i data (registers) ----
    const float4 qa = reinterpret_cast<const float4*>(q)[(size_t)i * 2];
    const float4 qb = reinterpret_cast<const float4*>(q)[(size_t)i * 2 + 1];
    const float rx = r[(size_t)i * 3 + 0];
    const float ry = r[(size_t)i * 3 + 1];
    const float rz = r[(size_t)i * 3 + 2];

    float acc = 0.0f;

#pragma unroll 4
    for (int jj = 0; jj < KC; ++jj) {
        const float4 pa = *reinterpret_cast<const float4*>(&s_q[jj][0]);  // uniform -> broadcast
        const float4 pb = *reinterpret_cast<const float4*>(&s_q[jj][4]);
        const float4 pr = *reinterpret_cast<const float4*>(&s_r[jj][0]);

        const float dx = pr.x - rx, dy = pr.y - ry, dz = pr.z - rz;
        const float d2 = dx * dx + dy * dy + dz * dz;

        float dot = qa.x * pa.x + qa.y * pa.y + qa.z * pa.z + qa.w * pa.w
                  + qb.x * pb.x + qb.y * pb.y + qb.z * pb.z + qb.w * pb.w;

        const float invd = __builtin_amdgcn_rsqf(d2);        // 1/d
        const float d    = d2 * invd;                        // d
        const float x    = d * 0.70710678118654752f;         // d/sqrt(2)
        // erf(x) = 1 - poly(t)*exp(-x^2), t = 1/(1+0.3275911 x)   [A&S 7.1.26]
        const float t = __builtin_amdgcn_rcpf(__builtin_fmaf(0.3275911f, x, 1.0f));
        const float e = __expf(-0.5f * d2);                  // exp(-x^2) = exp(-d2/2)
        const float p = t * (0.254829592f + t * (-0.284496736f +
                        t * (1.421413741f + t * (-1.453152027f + t * 1.061405429f))));
        const float erfv = __builtin_fmaf(-p, e, 1.0f);

        const float term = dot * erfv * invd;
        const bool  ok   = (!diag) | (j0 + jj > i);          // diag rect: keep j>i only
        acc += ok ? term : 0.0f;                             // select: inf/NaN at j==i discarded
    }

    // ---- block reduction -> one partial per block ----
    for (int off = 32; off > 0; off >>= 1)
        acc += __shfl_down(acc, off, 64);
    if ((tid & 63) == 0) s_part[tid >> 6] = acc;
    __syncthreads();
    if (tid == 0)
        partials[blockIdx.x] = s_part[0] + s_part[1] + s_part[2] + s_part[3];
}

__global__ void finalize_kernel(const float* __restrict__ partials,
                                float* __restrict__ out, int nb) {
    const int tid = threadIdx.x;  // 64 threads, single wave
    double s = 0.0;
    for (int idx = tid; idx < nb; idx += 64) s += (double)partials[idx];
    for (int off = 32; off > 0; off >>= 1)
        s += __shfl_down(s, off, 64);
    if (tid == 0) {
        // half-sum doubled, then * NORM/(2pi)/2  =>  * NORM/(2pi)
        out[0] = (float)(s * (90.0474 / 6.283185307179586));
    }
}

extern "C" void kernel_launch(void* const* d_in, const int* in_sizes, int n_in,
                              void* d_out, int out_size, void* d_ws, size_t ws_size,
                              hipStream_t stream) {
    const float* q = (const float*)d_in[0];   // [n, 8]
    const float* r = (const float*)d_in[1];   // [n, 3]
    float* out      = (float*)d_out;
    float* partials = (float*)d_ws;

    const int n  = in_sizes[1] / 3;           // 4096
    const int nt = n / TILE;                  // 16
    const int nrects = nt * (nt + 1) / 2;     // 136 unordered tile pairs
    const int nblocks = nrects * CHUNKS;      // 544

    ewald_pairs_kernel<<<nblocks, 256, 0, stream>>>(q, r, partials, n);
    finalize_kernel<<<1, 64, 0, stream>>>(partials, out, nblocks);
}

// Round 3
// 69.145 us; speedup vs baseline: 1.4439x; 1.0951x over previous
//
#include <hip/hip_runtime.h>
#include <math.h>

// Ewald real-space pair sum, symmetric half-enumeration:
//   out = (NORM / 2pi) * sum_{i<j} dot(q_i,q_j) * erf(d_ij/sqrt(2)) / d_ij
// n = 4096, n_q = 8, fp32.
// erf via Abramowitz-Stegun 7.1.26 (|err| <= 1.5e-7), branchless.
// j-side data read via wave-uniform global loads (scalarize to s_load, no LDS).

#define TILE   256
#define KC     32
#define CHUNKS (TILE / KC)   // 8

#if __has_builtin(__builtin_amdgcn_exp2f)
#define EXP2F(x) __builtin_amdgcn_exp2f(x)
#else
#define EXP2F(x) __expf((x) * 0.69314718055994531f)
#endif

__device__ __forceinline__ float pair_term(float d2, float dot) {
    const float invd = __builtin_amdgcn_rsqf(d2);                 // 1/d
    const float x    = d2 * invd * 0.70710678118654752f;          // d/sqrt(2)
    // erf(x) = 1 - poly(t)*exp(-x^2), t = 1/(1 + 0.3275911 x)
    const float t = __builtin_amdgcn_rcpf(__builtin_fmaf(0.3275911f, x, 1.0f));
    const float e = EXP2F(d2 * -0.72134752044448170f);            // exp(-d2/2)
    const float p = t * (0.254829592f + t * (-0.284496736f +
                    t * (1.421413741f + t * (-1.453152027f + t * 1.061405429f))));
    const float erfv = __builtin_fmaf(-p, e, 1.0f);
    return dot * erfv * invd;
}

template <bool DIAG>
__device__ __forceinline__ float rect_loop(
    const float* __restrict__ qj, const float* __restrict__ rj,
    const float4 qa, const float4 qb,
    float rx, float ry, float rz, int j0, int i)
{
    float acc = 0.0f;
#pragma unroll 4
    for (int jj = 0; jj < KC; ++jj) {
        // wave-uniform addresses -> scalar loads
        const float dx = rj[jj * 3 + 0] - rx;
        const float dy = rj[jj * 3 + 1] - ry;
        const float dz = rj[jj * 3 + 2] - rz;
        const float d2 = dx * dx + dy * dy + dz * dz;

        float dot = qa.x * qj[jj * 8 + 0] + qa.y * qj[jj * 8 + 1]
                  + qa.z * qj[jj * 8 + 2] + qa.w * qj[jj * 8 + 3]
                  + qb.x * qj[jj * 8 + 4] + qb.y * qj[jj * 8 + 5]
                  + qb.z * qj[jj * 8 + 6] + qb.w * qj[jj * 8 + 7];

        const float term = pair_term(d2, dot);
        if (DIAG) {
            acc += (j0 + jj > i) ? term : 0.0f;  // mask j<=i (incl. the inf at j==i)
        } else {
            acc += term;
        }
    }
    return acc;
}

__global__ __launch_bounds__(256) void ewald_pairs_kernel(
    const float* __restrict__ q,   // [n][8]
    const float* __restrict__ r,   // [n][3]
    float* __restrict__ partials)  // [gridDim.x]
{
    __shared__ float s_part[4];

    const int tid   = threadIdx.x;
    const int rid   = blockIdx.x / CHUNKS;
    const int chunk = blockIdx.x % CHUNKS;

    // triangular decode: rid -> (col <= row)
    int row = (int)((sqrtf(8.0f * (float)rid + 1.0f) - 1.0f) * 0.5f);
    while ((row + 1) * (row + 2) / 2 <= rid) ++row;
    while (row * (row + 1) / 2 > rid) --row;
    const int col = rid - row * (row + 1) / 2;

    const int i  = col * TILE + tid;
    const int j0 = row * TILE + chunk * KC;

    // per-lane i data
    const float4 qa = reinterpret_cast<const float4*>(q)[(size_t)i * 2];
    const float4 qb = reinterpret_cast<const float4*>(q)[(size_t)i * 2 + 1];
    const float rx = r[(size_t)i * 3 + 0];
    const float ry = r[(size_t)i * 3 + 1];
    const float rz = r[(size_t)i * 3 + 2];

    const float* __restrict__ qj = q + (size_t)j0 * 8;
    const float* __restrict__ rj = r + (size_t)j0 * 3;

    float acc = (col != row)
        ? rect_loop<false>(qj, rj, qa, qb, rx, ry, rz, j0, i)
        : rect_loop<true >(qj, rj, qa, qb, rx, ry, rz, j0, i);

    // block reduction -> one partial per block
    for (int off = 32; off > 0; off >>= 1)
        acc += __shfl_down(acc, off, 64);
    if ((tid & 63) == 0) s_part[tid >> 6] = acc;
    __syncthreads();
    if (tid == 0)
        partials[blockIdx.x] = s_part[0] + s_part[1] + s_part[2] + s_part[3];
}

__global__ __launch_bounds__(256) void finalize_kernel(
    const float* __restrict__ partials, float* __restrict__ out, int nb)
{
    __shared__ double sp[4];
    const int tid = threadIdx.x;
    double s = 0.0;
    for (int idx = tid; idx < nb; idx += 256) s += (double)partials[idx];
    for (int off = 32; off > 0; off >>= 1)
        s += __shfl_down(s, off, 64);
    if ((tid & 63) == 0) sp[tid >> 6] = s;
    __syncthreads();
    if (tid == 0) {
        const double tot = sp[0] + sp[1] + sp[2] + sp[3];
        // half-sum doubled, then * NORM/(2pi)/2  =>  * NORM/(2pi)
        out[0] = (float)(tot * (90.0474 / 6.283185307179586));
    }
}

extern "C" void kernel_launch(void* const* d_in, const int* in_sizes, int n_in,
                              void* d_out, int out_size, void* d_ws, size_t ws_size,
                              hipStream_t stream) {
    const float* q = (const float*)d_in[0];   // [n, 8]
    const float* r = (const float*)d_in[1];   // [n, 3]
    float* out      = (float*)d_out;
    float* partials = (float*)d_ws;

    const int n  = in_sizes[1] / 3;           // 4096
    const int nt = n / TILE;                  // 16
    const int nrects  = nt * (nt + 1) / 2;    // 136
    const int nblocks = nrects * CHUNKS;      // 1088

    ewald_pairs_kernel<<<nblocks, 256, 0, stream>>>(q, r, partials);
    finalize_kernel<<<1, 256, 0, stream>>>(partials, out, nblocks);
}